// Round 5
// baseline (210.702 us; speedup 1.0000x reference)
//
#include <hip/hip_runtime.h>

#define DD 256
#define HH 256
#define WW 256
#define RMAX 6

// tiles: 64 x 64 x 16 tiles of 4 x 4 x 16 voxels. tile id = (tx<<10)|(ty<<4)|tz
#define NTILES 65536
#define CAP 24        // inline records per tile (lambda ~5; ovf path covers excess)
#define RECSZ 16      // floats per record (64 B)
#define OVF_CAP 8192

// ---------------- binning: TWO GAUSSIANS PER WAVE (32 lanes each), lanes = tiles ----------
__global__ __launch_bounds__(256) void fill_kernel(
    const float* __restrict__ center, const float* __restrict__ cov_inv,
    const float* __restrict__ dens_r, const float* __restrict__ dens_i,
    const float* __restrict__ radius, const float* __restrict__ half_shape,
    int* __restrict__ tile_cnt, float* __restrict__ tile_recs,
    int* __restrict__ ovf_cnt, int* __restrict__ ovf_list, int N)
{
    int lane32 = threadIdx.x & 31;
    int i = blockIdx.x * 8 + (threadIdx.x >> 5);   // 8 half-waves per 256-thread block
    if (i >= N) return;

    float cx = center[3*i+0], cy = center[3*i+1], cz = center[3*i+2];
    float r  = radius[i];
    // cov_inv is exactly symmetric by construction (A A^T + I scaled)
    float c00=cov_inv[9*i+0], c01=cov_inv[9*i+1], c02=cov_inv[9*i+2];
    float c11=cov_inv[9*i+4], c12=cov_inv[9*i+5], c22=cov_inv[9*i+8];

    // ellipsoid extents: |d_axis| > sqrt(9*(M^-1)_ii) (normalized) => Md > 9 strictly,
    // so tightening the bbox to the extent is exact w.r.t. the reference mask.
    float d00 = c11*c22 - c12*c12;
    float d11 = c00*c22 - c02*c02;
    float d22 = c00*c11 - c01*c01;
    float det = c00*d00 - c01*(c01*c22 - c02*c12) + c02*(c01*c12 - c02*c11);
    float k9  = 9.0f / det;          // det > 0 (SPD)
    float hx = half_shape[0], hy = half_shape[1], hz = half_shape[2];
    float ex = hx * sqrtf(d00 * k9) * 1.0001f + 0.01f;
    float ey = hy * sqrtf(d11 * k9) * 1.0001f + 0.01f;
    float ez = hz * sqrtf(d22 * k9) * 1.0001f + 0.01f;
    float rx = fminf(r, ex), ry = fminf(r, ey), rz = fminf(r, ez);

    int bx=(int)floorf(cx), by=(int)floorf(cy), bz=(int)floorf(cz);
    int xlo = max(max((int)floorf(cx - rx), bx - RMAX), 0);
    int xhi = min(min((int)ceilf (cx + rx), bx + RMAX), DD - 1);
    int ylo = max(max((int)floorf(cy - ry), by - RMAX), 0);
    int yhi = min(min((int)ceilf (cy + ry), by + RMAX), HH - 1);
    int zlo = max(max((int)floorf(cz - rz), bz - RMAX), 0);
    int zhi = min(min((int)ceilf (cz + rz), bz + RMAX), WW - 1);
    if (xlo > xhi || ylo > yhi || zlo > zhi) return;

    int tx0 = xlo >> 2, ntx = (xhi >> 2) - tx0 + 1;
    int ty0 = ylo >> 2, nty = (yhi >> 2) - ty0 + 1;
    int tz0 = zlo >> 4, ntz = (zhi >> 4) - tz0 + 1;
    int ntiles = ntx * nty * ntz;          // <= 4*4*2 = 32 <= 32 lanes per half-wave

    if (lane32 >= ntiles) return;

    unsigned lo = (unsigned)xlo | ((unsigned)ylo << 8) | ((unsigned)zlo << 16);
    unsigned hi = (unsigned)xhi | ((unsigned)yhi << 8) | ((unsigned)zhi << 16);
    float4 r0 = make_float4(cx, cy, cz, c00);
    float4 r1 = make_float4(c11, c22, c01 + c01, c02 + c02);
    float4 r2 = make_float4(c12 + c12, dens_r[i], dens_i[i], __uint_as_float(lo));
    float4 r3 = make_float4(__uint_as_float(hi), 0.f, 0.f, 0.f);

    int t = lane32;
    int tzz = tz0 + (t % ntz); t /= ntz;
    int tyy = ty0 + (t % nty); t /= nty;
    int txx = tx0 + t;
    int tile = (txx << 10) | (tyy << 4) | tzz;

    int pos = atomicAdd(&tile_cnt[tile], 1);
    if (pos < CAP) {
        float4* R = (float4*)(tile_recs + ((size_t)tile * CAP + pos) * RECSZ);
        R[0] = r0; R[1] = r1; R[2] = r2; R[3] = r3;
    } else {
        int o = atomicAdd(ovf_cnt, 1);
        if (o < OVF_CAP) { ovf_list[2*o] = tile; ovf_list[2*o+1] = i; }
    }
}

// ---------------- gather: 4 tiles/block, per-wave LDS staging, write-once ----------------
// LDS staging (R2/R4 A/B: >= SGPR broadcast loads): lane-parallel staging issues record
// loads in one VMEM batch, re-read via conflict-free LDS broadcasts. First 4 records are
// staged BLIND (no dependence on tile_cnt) to overlap the count-load latency.
// Overflow handling is folded in: each wave checks ovf_cnt (expected 0) and, if set,
// accumulates matching entries from raw inputs BEFORE its single write -> no ovf kernel.
__global__ __launch_bounds__(256) void gather_kernel(
    const int* __restrict__ tile_cnt, const float* __restrict__ tile_recs,
    const float* __restrict__ half_shape,
    const int* __restrict__ ovf_cnt, const int* __restrict__ ovf_list,
    const float* __restrict__ center, const float* __restrict__ cov_inv,
    const float* __restrict__ dens_r, const float* __restrict__ dens_i,
    const float* __restrict__ radius,
    float* __restrict__ vol_r, float* __restrict__ vol_i)
{
    __shared__ float4 lds[4 * CAP * 4];   // 6 KB, disjoint per wave
    int w = threadIdx.x >> 6, lane = threadIdx.x & 63;
    int tile = (blockIdx.x << 2) | w;
    int tz = tile & 15, ty = (tile >> 4) & 63, tx = tile >> 10;
    int dxl = lane >> 4, dyl = (lane >> 2) & 3, dzq = lane & 3;
    int vx = tx*4 + dxl, vy = ty*4 + dyl, vz0 = tz*16 + dzq*4;
    float vxf = (float)vx, vyf = (float)vy, vz0f = (float)vz0;
    float ihx = 1.0f/half_shape[0], ihy = 1.0f/half_shape[1], ihz = 1.0f/half_shape[2];

    float4* wl = lds + w * (CAP * 4);
    const float4* src = (const float4*)(tile_recs + (size_t)tile * CAP * RECSZ);

    // blind-stage first 4 records (16 float4) with no dependence on the count load;
    // garbage beyond the real count is never read (loop bound n).
    if (lane < 16) wl[lane] = src[lane];
    int ocnt = min(ovf_cnt[0], OVF_CAP);         // expected 0; L2-broadcast
    int n = min(tile_cnt[tile], CAP);
    for (int idx = 16 + lane; idx < n * 4; idx += 64) wl[idx] = src[idx];
    // no __syncthreads: each wave reads only the LDS region it wrote itself

    float ar0=0.f, ar1=0.f, ar2=0.f, ar3=0.f;
    float ai0=0.f, ai1=0.f, ai2=0.f, ai3=0.f;

    for (int j = 0; j < n; ++j) {
        float4 r0 = wl[j*4+0];
        float4 r1 = wl[j*4+1];
        float4 r2 = wl[j*4+2];
        float4 r3 = wl[j*4+3];
        float cx=r0.x, cy=r0.y, cz=r0.z, s00=r0.w;
        float s11=r1.x, s22=r1.y, s01=r1.z, s02=r1.w;
        float s12=r2.x, dr=r2.y, di=r2.z;
        unsigned lo = __float_as_uint(r2.w), hi = __float_as_uint(r3.x);
        int xlo = lo & 255, ylo = (lo >> 8) & 255, zlo = (lo >> 16) & 255;
        int xhi = hi & 255, yhi = (hi >> 8) & 255, zhi = (hi >> 16) & 255;

        // unsigned-range trick: vx<xlo wraps to huge -> false
        bool okxy = ((unsigned)(vx - xlo) <= (unsigned)(xhi - xlo)) &
                    ((unsigned)(vy - ylo) <= (unsigned)(yhi - ylo));
        int iz0 = vz0 - zlo;
        unsigned zspan = (unsigned)(zhi - zlo);

        float fx = (vxf - cx) * ihx;
        float fy = (vyf - cy) * ihy;
        float axy = fx*fx*s00 + fx*fy*s01 + fy*fy*s11;
        float bxy = fx*s02 + fy*s12;
        float nczihz = -cz * ihz;

        float fz0 = fmaf(vz0f, ihz, nczihz);
        float fz1 = fz0 + ihz;
        float fz2 = fz1 + ihz;
        float fz3 = fz2 + ihz;
        float md0 = fmaf(fz0, fmaf(s22, fz0, bxy), axy);
        float md1 = fmaf(fz1, fmaf(s22, fz1, bxy), axy);
        float md2 = fmaf(fz2, fmaf(s22, fz2, bxy), axy);
        float md3 = fmaf(fz3, fmaf(s22, fz3, bxy), axy);

        bool ok0 = okxy & ((unsigned)(iz0    ) <= zspan) & (md0 <= 9.0f);
        bool ok1 = okxy & ((unsigned)(iz0 + 1) <= zspan) & (md1 <= 9.0f);
        bool ok2 = okxy & ((unsigned)(iz0 + 2) <= zspan) & (md2 <= 9.0f);
        bool ok3 = okxy & ((unsigned)(iz0 + 3) <= zspan) & (md3 <= 9.0f);

        if (__any(ok0 | ok1 | ok2 | ok3)) {
            // exp(-0.5*md) == exp2(md * -0.5*log2(e)) : saves one v_mul per voxel
            const float kexp = -0.72134752044448169f;
            float w0 = ok0 ? exp2f(md0 * kexp) : 0.0f;
            float w1 = ok1 ? exp2f(md1 * kexp) : 0.0f;
            float w2 = ok2 ? exp2f(md2 * kexp) : 0.0f;
            float w3 = ok3 ? exp2f(md3 * kexp) : 0.0f;
            ar0 = fmaf(w0, dr, ar0); ai0 = fmaf(w0, di, ai0);
            ar1 = fmaf(w1, dr, ar1); ai1 = fmaf(w1, di, ai1);
            ar2 = fmaf(w2, dr, ar2); ai2 = fmaf(w2, di, ai2);
            ar3 = fmaf(w3, dr, ar3); ai3 = fmaf(w3, di, ai3);
        }
    }

    // ---- overflow fold-in (dormant: ocnt expected 0). Reference-exact semantics. ----
    if (ocnt > 0) {
        for (int p = 0; p < ocnt; ++p) {
            if (ovf_list[2*p] != tile) continue;
            int g = ovf_list[2*p+1];
            float cx = center[3*g+0], cy = center[3*g+1], cz = center[3*g+2];
            float r  = radius[g];
            float c00=cov_inv[9*g+0], c01=cov_inv[9*g+1], c02=cov_inv[9*g+2];
            float c11=cov_inv[9*g+4], c12=cov_inv[9*g+5], c22=cov_inv[9*g+8];
            float dr = dens_r[g], di = dens_i[g];
            int bx=(int)floorf(cx), by=(int)floorf(cy), bz=(int)floorf(cz);
            int xlo = max(max((int)floorf(cx - r), bx - RMAX), 0);
            int xhi = min(min((int)ceilf (cx + r), bx + RMAX), DD - 1);
            int ylo = max(max((int)floorf(cy - r), by - RMAX), 0);
            int yhi = min(min((int)ceilf (cy + r), by + RMAX), HH - 1);
            int zlo = max(max((int)floorf(cz - r), bz - RMAX), 0);
            int zhi = min(min((int)ceilf (cz + r), bz + RMAX), WW - 1);
            if (vx < xlo || vx > xhi || vy < ylo || vy > yhi) continue;
            float fx = (vxf - cx) * ihx;
            float fy = (vyf - cy) * ihy;
            float axy = fx*fx*c00 + 2.0f*fx*fy*c01 + fy*fy*c11;
            float bxy = 2.0f*(fx*c02 + fy*c12);
            #pragma unroll
            for (int k = 0; k < 4; ++k) {
                int vz = vz0 + k;
                float fz = ((float)vz - cz) * ihz;
                float md = fmaf(fz, fmaf(c22, fz, bxy), axy);
                if (vz >= zlo && vz <= zhi && md <= 9.0f) {
                    float wgt = __expf(-0.5f * md);
                    if (k == 0) { ar0 = fmaf(wgt, dr, ar0); ai0 = fmaf(wgt, di, ai0); }
                    if (k == 1) { ar1 = fmaf(wgt, dr, ar1); ai1 = fmaf(wgt, di, ai1); }
                    if (k == 2) { ar2 = fmaf(wgt, dr, ar2); ai2 = fmaf(wgt, di, ai2); }
                    if (k == 3) { ar3 = fmaf(wgt, dr, ar3); ai3 = fmaf(wgt, di, ai3); }
                }
            }
        }
    }

    size_t flat = ((size_t)vx * HH + vy) * WW + vz0;   // vz0 % 4 == 0 -> 16B aligned
    *(float4*)(vol_r + flat) = make_float4(ar0, ar1, ar2, ar3);
    *(float4*)(vol_i + flat) = make_float4(ai0, ai1, ai2, ai3);
}

// ---------------- fallback scatter (only if ws too small) ----------------
__global__ __launch_bounds__(256) void splat_kernel(
    const float* __restrict__ center, const float* __restrict__ cov_inv,
    const float* __restrict__ dens_r, const float* __restrict__ dens_i,
    const float* __restrict__ radius, const float* __restrict__ half_shape,
    float* __restrict__ vol_r, float* __restrict__ vol_i, int N)
{
    int g = blockIdx.x;
    if (g >= N) return;
    float cx = center[3*g+0], cy = center[3*g+1], cz = center[3*g+2];
    float r  = radius[g];
    float c00 = cov_inv[9*g+0], c01 = cov_inv[9*g+1], c02 = cov_inv[9*g+2];
    float c10 = cov_inv[9*g+3], c11 = cov_inv[9*g+4], c12 = cov_inv[9*g+5];
    float c20 = cov_inv[9*g+6], c21 = cov_inv[9*g+7], c22 = cov_inv[9*g+8];
    float dr = dens_r[g], di = dens_i[g];
    float ihx = 1.0f/half_shape[0], ihy = 1.0f/half_shape[1], ihz = 1.0f/half_shape[2];
    int bx = (int)floorf(cx), by = (int)floorf(cy), bz = (int)floorf(cz);
    int xlo = max(max((int)floorf(cx - r), bx - RMAX), 0);
    int xhi = min(min((int)ceilf (cx + r), bx + RMAX), DD - 1);
    int ylo = max(max((int)floorf(cy - r), by - RMAX), 0);
    int yhi = min(min((int)ceilf (cy + r), by + RMAX), HH - 1);
    int zlo = max(max((int)floorf(cz - r), bz - RMAX), 0);
    int zhi = min(min((int)ceilf (cz + r), bz + RMAX), WW - 1);
    int nx = xhi-xlo+1, ny = yhi-ylo+1, nz = zhi-zlo+1;
    if (nx <= 0 || ny <= 0 || nz <= 0) return;
    int total = nx*ny*nz;
    for (int k = threadIdx.x; k < total; k += 256) {
        int iz = k % nz, tq = k / nz, iy = tq % ny, ix = tq / ny;
        int vx = xlo+ix, vy = ylo+iy, vz = zlo+iz;
        float dxn = ((float)vx - cx) * ihx;
        float dyn = ((float)vy - cy) * ihy;
        float dzn = ((float)vz - cz) * ihz;
        float md = dxn*(c00*dxn + c01*dyn + c02*dzn)
                 + dyn*(c10*dxn + c11*dyn + c12*dzn)
                 + dzn*(c20*dxn + c21*dyn + c22*dzn);
        if (md <= 9.0f) {
            float wgt = __expf(-0.5f*md);
            int flat = (vx*HH + vy)*WW + vz;
            atomicAdd(&vol_r[flat], wgt*dr);
            atomicAdd(&vol_i[flat], wgt*di);
        }
    }
}

extern "C" void kernel_launch(void* const* d_in, const int* in_sizes, int n_in,
                              void* d_out, int out_size, void* d_ws, size_t ws_size,
                              hipStream_t stream) {
    const float* center     = (const float*)d_in[0];
    const float* cov_inv    = (const float*)d_in[1];
    const float* dens_r     = (const float*)d_in[2];
    const float* dens_i     = (const float*)d_in[3];
    const float* radius     = (const float*)d_in[4];
    const float* half_shape = (const float*)d_in[5];
    int N = in_sizes[0] / 3;

    float* vol_r = (float*)d_out;
    float* vol_i = vol_r + (size_t)DD * HH * WW;

    // ws layout: [tile_recs | tile_cnt | ovf_cnt | ovf_list]
    size_t rec_floats = (size_t)NTILES * CAP * RECSZ;           // ~100.7 MB
    size_t need = rec_floats * sizeof(float)
                + ((size_t)NTILES + 4 + 2*OVF_CAP) * sizeof(int);
    if (ws_size < need) {
        (void)hipMemsetAsync(d_out, 0, (size_t)out_size * sizeof(float), stream);
        splat_kernel<<<N, 256, 0, stream>>>(center, cov_inv, dens_r, dens_i,
                                            radius, half_shape, vol_r, vol_i, N);
        return;
    }

    float* tile_recs = (float*)d_ws;
    int*   tile_cnt  = (int*)(tile_recs + rec_floats);   // NTILES
    int*   ovf_cnt   = tile_cnt + NTILES;                // 4
    int*   ovf_list  = ovf_cnt + 4;                      // 2*OVF_CAP

    (void)hipMemsetAsync(tile_cnt, 0, ((size_t)NTILES + 4) * sizeof(int), stream);
    // two gaussians per wave: 8 gaussians per 256-thread block
    fill_kernel<<<(N + 7)/8, 256, 0, stream>>>(center, cov_inv, dens_r, dens_i,
                                               radius, half_shape,
                                               tile_cnt, tile_recs,
                                               ovf_cnt, ovf_list, N);
    gather_kernel<<<NTILES/4, 256, 0, stream>>>(tile_cnt, tile_recs, half_shape,
                                                ovf_cnt, ovf_list,
                                                center, cov_inv, dens_r, dens_i,
                                                radius, vol_r, vol_i);
}

// Round 6
// 205.859 us; speedup vs baseline: 1.0235x; 1.0235x over previous
//
#include <hip/hip_runtime.h>

#define DD 256
#define HH 256
#define WW 256
#define RMAX 6

// tiles: 64 x 64 x 16 tiles of 4 x 4 x 16 voxels. tile id = (tx<<10)|(ty<<4)|tz
#define NTILES 65536
#define CAP 24        // inline records per tile (lambda ~5; ovf net covers excess)
#define RECSZ 16      // floats per record (64 B)
#define OVF_CAP 8192

// ---------------- binning: ONE WAVE PER GAUSSIAN, lanes = overlapped tiles ----------------
// wave-uniform gaussian index (readfirstlane): all per-gaussian loads are scalar
// (s_load), bbox math is computed once per wave on SALU-friendly uniform values.
// Measured better than 2-gaussians-per-wave divergent variant (R5: 210.7 vs 206.0).
__global__ __launch_bounds__(256) void fill_kernel(
    const float* __restrict__ center, const float* __restrict__ cov_inv,
    const float* __restrict__ dens_r, const float* __restrict__ dens_i,
    const float* __restrict__ radius, const float* __restrict__ half_shape,
    int* __restrict__ tile_cnt, float* __restrict__ tile_recs,
    int* __restrict__ ovf_cnt, int* __restrict__ ovf_list, int N)
{
    int lane = threadIdx.x & 63;
    int i = __builtin_amdgcn_readfirstlane(blockIdx.x * 4 + (threadIdx.x >> 6));
    if (i >= N) return;

    float cx = center[3*i+0], cy = center[3*i+1], cz = center[3*i+2];
    float r  = radius[i];
    // cov_inv is exactly symmetric by construction (A A^T + I scaled)
    float c00=cov_inv[9*i+0], c01=cov_inv[9*i+1], c02=cov_inv[9*i+2];
    float c11=cov_inv[9*i+4], c12=cov_inv[9*i+5], c22=cov_inv[9*i+8];

    // ellipsoid extents: |d_axis| > sqrt(9*(M^-1)_ii) (normalized) => Md > 9 strictly,
    // so tightening the bbox to the extent is exact w.r.t. the reference mask.
    float d00 = c11*c22 - c12*c12;
    float d11 = c00*c22 - c02*c02;
    float d22 = c00*c11 - c01*c01;
    float det = c00*d00 - c01*(c01*c22 - c02*c12) + c02*(c01*c12 - c02*c11);
    float k9  = 9.0f / det;          // det > 0 (SPD)
    float hx = half_shape[0], hy = half_shape[1], hz = half_shape[2];
    float ex = hx * sqrtf(d00 * k9) * 1.0001f + 0.01f;
    float ey = hy * sqrtf(d11 * k9) * 1.0001f + 0.01f;
    float ez = hz * sqrtf(d22 * k9) * 1.0001f + 0.01f;
    float rx = fminf(r, ex), ry = fminf(r, ey), rz = fminf(r, ez);

    int bx=(int)floorf(cx), by=(int)floorf(cy), bz=(int)floorf(cz);
    int xlo = max(max((int)floorf(cx - rx), bx - RMAX), 0);
    int xhi = min(min((int)ceilf (cx + rx), bx + RMAX), DD - 1);
    int ylo = max(max((int)floorf(cy - ry), by - RMAX), 0);
    int yhi = min(min((int)ceilf (cy + ry), by + RMAX), HH - 1);
    int zlo = max(max((int)floorf(cz - rz), bz - RMAX), 0);
    int zhi = min(min((int)ceilf (cz + rz), bz + RMAX), WW - 1);
    if (xlo > xhi || ylo > yhi || zlo > zhi) return;

    int tx0 = xlo >> 2, ntx = (xhi >> 2) - tx0 + 1;
    int ty0 = ylo >> 2, nty = (yhi >> 2) - ty0 + 1;
    int tz0 = zlo >> 4, ntz = (zhi >> 4) - tz0 + 1;
    int ntiles = ntx * nty * ntz;          // <= 4*4*2 = 32 <= 64 lanes

    if (lane >= ntiles) return;

    unsigned lo = (unsigned)xlo | ((unsigned)ylo << 8) | ((unsigned)zlo << 16);
    unsigned hi = (unsigned)xhi | ((unsigned)yhi << 8) | ((unsigned)zhi << 16);
    float4 r0 = make_float4(cx, cy, cz, c00);
    float4 r1 = make_float4(c11, c22, c01 + c01, c02 + c02);
    float4 r2 = make_float4(c12 + c12, dens_r[i], dens_i[i], __uint_as_float(lo));
    float4 r3 = make_float4(__uint_as_float(hi), 0.f, 0.f, 0.f);

    int t = lane;
    int tzz = tz0 + (t % ntz); t /= ntz;
    int tyy = ty0 + (t % nty); t /= nty;
    int txx = tx0 + t;
    int tile = (txx << 10) | (tyy << 4) | tzz;

    int pos = atomicAdd(&tile_cnt[tile], 1);
    if (pos < CAP) {
        float4* R = (float4*)(tile_recs + ((size_t)tile * CAP + pos) * RECSZ);
        R[0] = r0; R[1] = r1; R[2] = r2; R[3] = r3;
    } else {
        int o = atomicAdd(ovf_cnt, 1);
        if (o < OVF_CAP) { ovf_list[2*o] = tile; ovf_list[2*o+1] = i; }
    }
}

// ---------------- gather: 4 tiles/block, per-wave LDS staging, write-once ----------------
// LDS staging measured >= all tried alternatives (R2: SGPR broadcast loads 207.8;
// R5: blind-stage + ovf fold-in 210.7; this form 200.4/206.0). Lane-parallel staging
// issues all record loads in one VMEM batch (one exposed HBM latency per tile), then
// records are re-read via conflict-free LDS broadcasts. No __syncthreads needed: each
// wave reads only the LDS region it wrote itself.
__global__ __launch_bounds__(256) void gather_kernel(
    const int* __restrict__ tile_cnt, const float* __restrict__ tile_recs,
    const float* __restrict__ half_shape,
    float* __restrict__ vol_r, float* __restrict__ vol_i)
{
    __shared__ float4 lds[4 * CAP * 4];   // 6 KB, disjoint per wave
    int w = threadIdx.x >> 6, lane = threadIdx.x & 63;
    int tile = (blockIdx.x << 2) | w;
    int tz = tile & 15, ty = (tile >> 4) & 63, tx = tile >> 10;
    int dxl = lane >> 4, dyl = (lane >> 2) & 3, dzq = lane & 3;
    int vx = tx*4 + dxl, vy = ty*4 + dyl, vz0 = tz*16 + dzq*4;
    float vxf = (float)vx, vyf = (float)vy, vz0f = (float)vz0;
    float ihx = 1.0f/half_shape[0], ihy = 1.0f/half_shape[1], ihz = 1.0f/half_shape[2];

    int n = min(tile_cnt[tile], CAP);
    float4* wl = lds + w * (CAP * 4);
    const float4* src = (const float4*)(tile_recs + (size_t)tile * CAP * RECSZ);
    for (int idx = lane; idx < n * 4; idx += 64) wl[idx] = src[idx];
    // no __syncthreads: each wave reads only the LDS region it wrote itself

    float ar0=0.f, ar1=0.f, ar2=0.f, ar3=0.f;
    float ai0=0.f, ai1=0.f, ai2=0.f, ai3=0.f;

    for (int j = 0; j < n; ++j) {
        float4 r0 = wl[j*4+0];
        float4 r1 = wl[j*4+1];
        float4 r2 = wl[j*4+2];
        float4 r3 = wl[j*4+3];
        float cx=r0.x, cy=r0.y, cz=r0.z, s00=r0.w;
        float s11=r1.x, s22=r1.y, s01=r1.z, s02=r1.w;
        float s12=r2.x, dr=r2.y, di=r2.z;
        unsigned lo = __float_as_uint(r2.w), hi = __float_as_uint(r3.x);
        int xlo = lo & 255, ylo = (lo >> 8) & 255, zlo = (lo >> 16) & 255;
        int xhi = hi & 255, yhi = (hi >> 8) & 255, zhi = (hi >> 16) & 255;

        // unsigned-range trick: vx<xlo wraps to huge -> false
        bool okxy = ((unsigned)(vx - xlo) <= (unsigned)(xhi - xlo)) &
                    ((unsigned)(vy - ylo) <= (unsigned)(yhi - ylo));
        int iz0 = vz0 - zlo;
        unsigned zspan = (unsigned)(zhi - zlo);

        float fx = (vxf - cx) * ihx;
        float fy = (vyf - cy) * ihy;
        float axy = fx*fx*s00 + fx*fy*s01 + fy*fy*s11;
        float bxy = fx*s02 + fy*s12;
        float nczihz = -cz * ihz;

        float fz0 = fmaf(vz0f, ihz, nczihz);
        float fz1 = fz0 + ihz;
        float fz2 = fz1 + ihz;
        float fz3 = fz2 + ihz;
        float md0 = fmaf(fz0, fmaf(s22, fz0, bxy), axy);
        float md1 = fmaf(fz1, fmaf(s22, fz1, bxy), axy);
        float md2 = fmaf(fz2, fmaf(s22, fz2, bxy), axy);
        float md3 = fmaf(fz3, fmaf(s22, fz3, bxy), axy);

        bool ok0 = okxy & ((unsigned)(iz0    ) <= zspan) & (md0 <= 9.0f);
        bool ok1 = okxy & ((unsigned)(iz0 + 1) <= zspan) & (md1 <= 9.0f);
        bool ok2 = okxy & ((unsigned)(iz0 + 2) <= zspan) & (md2 <= 9.0f);
        bool ok3 = okxy & ((unsigned)(iz0 + 3) <= zspan) & (md3 <= 9.0f);

        if (__any(ok0 | ok1 | ok2 | ok3)) {
            // exp(-0.5*md) == exp2(md * -0.5*log2(e)) : saves one v_mul per voxel
            const float kexp = -0.72134752044448169f;
            float w0 = ok0 ? exp2f(md0 * kexp) : 0.0f;
            float w1 = ok1 ? exp2f(md1 * kexp) : 0.0f;
            float w2 = ok2 ? exp2f(md2 * kexp) : 0.0f;
            float w3 = ok3 ? exp2f(md3 * kexp) : 0.0f;
            ar0 = fmaf(w0, dr, ar0); ai0 = fmaf(w0, di, ai0);
            ar1 = fmaf(w1, dr, ar1); ai1 = fmaf(w1, di, ai1);
            ar2 = fmaf(w2, dr, ar2); ai2 = fmaf(w2, di, ai2);
            ar3 = fmaf(w3, dr, ar3); ai3 = fmaf(w3, di, ai3);
        }
    }

    size_t flat = ((size_t)vx * HH + vy) * WW + vz0;   // vz0 % 4 == 0 -> 16B aligned
    *(float4*)(vol_r + flat) = make_float4(ar0, ar1, ar2, ar3);
    *(float4*)(vol_i + flat) = make_float4(ai0, ai1, ai2, ai3);
}

// ---------------- overflow safety net (expected empty), reads raw inputs ----------------
__global__ __launch_bounds__(64) void ovf_kernel(
    const int* __restrict__ ovf_cnt, const int* __restrict__ ovf_list,
    const float* __restrict__ center, const float* __restrict__ cov_inv,
    const float* __restrict__ dens_r, const float* __restrict__ dens_i,
    const float* __restrict__ radius, const float* __restrict__ half_shape,
    float* __restrict__ vol_r, float* __restrict__ vol_i)
{
    int total = min(ovf_cnt[0], OVF_CAP);
    float ihx = 1.0f/half_shape[0], ihy = 1.0f/half_shape[1], ihz = 1.0f/half_shape[2];
    int lane = threadIdx.x;
    for (int p = blockIdx.x; p < total; p += gridDim.x) {
        int tile = ovf_list[2*p], g = ovf_list[2*p+1];
        int tz = tile & 15, ty = (tile >> 4) & 63, tx = tile >> 10;
        int dxl = lane >> 4, dyl = (lane >> 2) & 3, dzq = lane & 3;
        int vx = tx*4 + dxl, vy = ty*4 + dyl, vz0 = tz*16 + dzq*4;

        float cx = center[3*g+0], cy = center[3*g+1], cz = center[3*g+2];
        float r  = radius[g];
        float c00=cov_inv[9*g+0], c01=cov_inv[9*g+1], c02=cov_inv[9*g+2];
        float c10=cov_inv[9*g+3], c11=cov_inv[9*g+4], c12=cov_inv[9*g+5];
        float c20=cov_inv[9*g+6], c21=cov_inv[9*g+7], c22=cov_inv[9*g+8];
        float dr = dens_r[g], di = dens_i[g];

        int bx=(int)floorf(cx), by=(int)floorf(cy), bz=(int)floorf(cz);
        int xlo = max(max((int)floorf(cx - r), bx - RMAX), 0);
        int xhi = min(min((int)ceilf (cx + r), bx + RMAX), DD - 1);
        int ylo = max(max((int)floorf(cy - r), by - RMAX), 0);
        int yhi = min(min((int)ceilf (cy + r), by + RMAX), HH - 1);
        int zlo = max(max((int)floorf(cz - r), bz - RMAX), 0);
        int zhi = min(min((int)ceilf (cz + r), bz + RMAX), WW - 1);

        if (vx < xlo || vx > xhi || vy < ylo || vy > yhi) continue;
        float fx = ((float)vx - cx) * ihx;
        float fy = ((float)vy - cy) * ihy;
        for (int k = 0; k < 4; ++k) {
            int vz = vz0 + k;
            float fz = ((float)vz - cz) * ihz;
            float md = fx*(c00*fx + c01*fy + c02*fz)
                     + fy*(c10*fx + c11*fy + c12*fz)
                     + fz*(c20*fx + c21*fy + c22*fz);
            if (vz >= zlo && vz <= zhi && md <= 9.0f) {
                float wgt = __expf(-0.5f * md);
                size_t flat = ((size_t)vx * HH + vy) * WW + vz;
                atomicAdd(&vol_r[flat], wgt * dr);
                atomicAdd(&vol_i[flat], wgt * di);
            }
        }
    }
}

// ---------------- fallback scatter (only if ws too small) ----------------
__global__ __launch_bounds__(256) void splat_kernel(
    const float* __restrict__ center, const float* __restrict__ cov_inv,
    const float* __restrict__ dens_r, const float* __restrict__ dens_i,
    const float* __restrict__ radius, const float* __restrict__ half_shape,
    float* __restrict__ vol_r, float* __restrict__ vol_i, int N)
{
    int g = blockIdx.x;
    if (g >= N) return;
    float cx = center[3*g+0], cy = center[3*g+1], cz = center[3*g+2];
    float r  = radius[g];
    float c00 = cov_inv[9*g+0], c01 = cov_inv[9*g+1], c02 = cov_inv[9*g+2];
    float c10 = cov_inv[9*g+3], c11 = cov_inv[9*g+4], c12 = cov_inv[9*g+5];
    float c20 = cov_inv[9*g+6], c21 = cov_inv[9*g+7], c22 = cov_inv[9*g+8];
    float dr = dens_r[g], di = dens_i[g];
    float ihx = 1.0f/half_shape[0], ihy = 1.0f/half_shape[1], ihz = 1.0f/half_shape[2];
    int bx = (int)floorf(cx), by = (int)floorf(cy), bz = (int)floorf(cz);
    int xlo = max(max((int)floorf(cx - r), bx - RMAX), 0);
    int xhi = min(min((int)ceilf (cx + r), bx + RMAX), DD - 1);
    int ylo = max(max((int)floorf(cy - r), by - RMAX), 0);
    int yhi = min(min((int)ceilf (cy + r), by + RMAX), HH - 1);
    int zlo = max(max((int)floorf(cz - r), bz - RMAX), 0);
    int zhi = min(min((int)ceilf (cz + r), bz + RMAX), WW - 1);
    int nx = xhi-xlo+1, ny = yhi-ylo+1, nz = zhi-zlo+1;
    if (nx <= 0 || ny <= 0 || nz <= 0) return;
    int total = nx*ny*nz;
    for (int k = threadIdx.x; k < total; k += 256) {
        int iz = k % nz, tq = k / nz, iy = tq % ny, ix = tq / ny;
        int vx = xlo+ix, vy = ylo+iy, vz = zlo+iz;
        float dxn = ((float)vx - cx) * ihx;
        float dyn = ((float)vy - cy) * ihy;
        float dzn = ((float)vz - cz) * ihz;
        float md = dxn*(c00*dxn + c01*dyn + c02*dzn)
                 + dyn*(c10*dxn + c11*dyn + c12*dzn)
                 + dzn*(c20*dxn + c21*dyn + c22*dzn);
        if (md <= 9.0f) {
            float wgt = __expf(-0.5f*md);
            int flat = (vx*HH + vy)*WW + vz;
            atomicAdd(&vol_r[flat], wgt*dr);
            atomicAdd(&vol_i[flat], wgt*di);
        }
    }
}

extern "C" void kernel_launch(void* const* d_in, const int* in_sizes, int n_in,
                              void* d_out, int out_size, void* d_ws, size_t ws_size,
                              hipStream_t stream) {
    const float* center     = (const float*)d_in[0];
    const float* cov_inv    = (const float*)d_in[1];
    const float* dens_r     = (const float*)d_in[2];
    const float* dens_i     = (const float*)d_in[3];
    const float* radius     = (const float*)d_in[4];
    const float* half_shape = (const float*)d_in[5];
    int N = in_sizes[0] / 3;

    float* vol_r = (float*)d_out;
    float* vol_i = vol_r + (size_t)DD * HH * WW;

    // ws layout: [tile_recs | tile_cnt | ovf_cnt | ovf_list]
    size_t rec_floats = (size_t)NTILES * CAP * RECSZ;           // ~100.7 MB
    size_t need = rec_floats * sizeof(float)
                + ((size_t)NTILES + 4 + 2*OVF_CAP) * sizeof(int);
    if (ws_size < need) {
        (void)hipMemsetAsync(d_out, 0, (size_t)out_size * sizeof(float), stream);
        splat_kernel<<<N, 256, 0, stream>>>(center, cov_inv, dens_r, dens_i,
                                            radius, half_shape, vol_r, vol_i, N);
        return;
    }

    float* tile_recs = (float*)d_ws;
    int*   tile_cnt  = (int*)(tile_recs + rec_floats);   // NTILES
    int*   ovf_cnt   = tile_cnt + NTILES;                // 4
    int*   ovf_list  = ovf_cnt + 4;                      // 2*OVF_CAP

    (void)hipMemsetAsync(tile_cnt, 0, ((size_t)NTILES + 4) * sizeof(int), stream);
    // one wave per gaussian: 4 gaussians per 256-thread block
    fill_kernel<<<(N + 3)/4, 256, 0, stream>>>(center, cov_inv, dens_r, dens_i,
                                               radius, half_shape,
                                               tile_cnt, tile_recs,
                                               ovf_cnt, ovf_list, N);
    gather_kernel<<<NTILES/4, 256, 0, stream>>>(tile_cnt, tile_recs, half_shape,
                                                vol_r, vol_i);
    ovf_kernel<<<64, 64, 0, stream>>>(ovf_cnt, ovf_list, center, cov_inv,
                                      dens_r, dens_i, radius, half_shape,
                                      vol_r, vol_i);
}